// Round 2
// baseline (968.365 us; speedup 1.0000x reference)
//
#include <hip/hip_runtime.h>
#include <stdint.h>

#define NTOK 65536
#define DIM  768
#define NCB  512
#define NC   510

typedef _Float16 f16x8 __attribute__((ext_vector_type(8)));
typedef float f32x4 __attribute__((ext_vector_type(4)));

// ws byte offsets
#define WS_C32   0u          // 512*768*4
#define WS_CHI   1572864u    // 512*768*2   (f16 hi)
#define WS_CLO   2359296u    // 512*768*2   (f16 (x-hi)*256)
#define WS_CNORM 3145728u    // 512*4
#define WS_G     3147776u    // 512*512*4
#define WS_IDX   4196352u    // 65536*8*4
#define WS_ACC   6293504u    // 4

__global__ void k_prep(const float* __restrict__ cb0, const float* __restrict__ cb1,
                       const float* __restrict__ cb2, const float* __restrict__ cb3,
                       const float* __restrict__ cb4, const float* __restrict__ cb5,
                       const float* __restrict__ cb6, const float* __restrict__ cb7,
                       char* __restrict__ ws){
  const int r = blockIdx.x, t = threadIdx.x;
  const float* srcs[8] = {cb0,cb1,cb2,cb3,cb4,cb5,cb6,cb7};
  const int off[8] = {0,2,6,14,30,62,126,254};
  const int KK[8]  = {2,4,8,16,32,64,128,256};
  const float* src = nullptr;
#pragma unroll
  for (int l=0;l<8;l++)
    if (r >= off[l] && r < off[l]+KK[l]) src = srcs[l] + (size_t)(r - off[l]) * DIM;
  float* C32 = (float*)(ws + WS_C32);
  _Float16* Chi = (_Float16*)(ws + WS_CHI);
  _Float16* Clo = (_Float16*)(ws + WS_CLO);
  double ss = 0.0;
#pragma unroll
  for (int i=0;i<3;i++){
    const int e = t + i*256;
    const float v = src ? src[e] : 0.f;
    C32[(size_t)r*DIM + e] = v;
    const _Float16 h = (_Float16)v;
    Chi[(size_t)r*DIM + e] = h;
    Clo[(size_t)r*DIM + e] = (_Float16)((v - (float)h) * 256.f);
    ss += (double)v * (double)v;
  }
  __shared__ double red[256];
  red[t] = ss; __syncthreads();
  for (int sdown=128; sdown>0; sdown>>=1){
    if (t < sdown) red[t] += red[t+sdown];
    __syncthreads();
  }
  if (t == 0){
    float* cnp = (float*)(ws + WS_CNORM);
    cnp[r] = (r < NC) ? (float)red[0] : 1e30f;
    if (r == 0) *(float*)(ws + WS_ACC) = 0.f;
  }
}

__global__ void k_gram(char* __restrict__ ws){
  const int i = blockIdx.x, t = threadIdx.x;
  const float* __restrict__ C32 = (const float*)(ws + WS_C32);
  __shared__ float row[DIM];
  for (int e=t; e<DIM; e+=256) row[e] = C32[(size_t)i*DIM + e];
  __syncthreads();
  float* __restrict__ G = (float*)(ws + WS_G);
  for (int j=t; j<NCB; j+=256){
    const float4* cj = (const float4*)(C32 + (size_t)j*DIM);
    double d = 0.0;
    for (int k=0; k<DIM/4; k++){
      const float4 b = cj[k];
      d += (double)row[4*k]*(double)b.x + (double)row[4*k+1]*(double)b.y
         + (double)row[4*k+2]*(double)b.z + (double)row[4*k+3]*(double)b.w;
    }
    G[(size_t)i*NCB + j] = (float)d;
  }
}

// Main: fused GEMM (S = x @ C_all^T, f16 hi/lo-scaled dual-accumulator) + argmin chain.
// BM=64 tokens, BN=512 (all candidates), BK=64, 8 waves (2M x 4N).
// LDS: S[512][64] f32 swizzled (131072B, staging aliased in first 32KB)
//      + part_val double[512] + part_idx u16[512].
__global__ __launch_bounds__(512, 2) void k_main(const float* __restrict__ x,
                                                 char* __restrict__ ws){
  __shared__ __align__(16) char smem[136192];
  const int t = threadIdx.x;
  const int lane = t & 63;
  const int w = t >> 6;
  const int wm = w >> 2;     // 0..1
  const int wn = w & 3;      // 0..3
  const int blk = blockIdx.x;

  const _Float16* __restrict__ Chi = (const _Float16*)(ws + WS_CHI);
  const _Float16* __restrict__ Clo = (const _Float16*)(ws + WS_CLO);

  f32x4 accA[2][8], accB[2][8];
#pragma unroll
  for (int i=0;i<2;i++)
#pragma unroll
    for (int j=0;j<8;j++){ accA[i][j] = {0.f,0.f,0.f,0.f}; accB[i][j] = {0.f,0.f,0.f,0.f}; }

  // staging geometry: 512 thr cover 64 rows x 64 cols f32 (8 f32/thread)
  const int srow = t >> 3;
  const int sc8  = (t & 7) * 8;
  const float* __restrict__ xbase = x + ((size_t)(blk*64 + srow))*DIM + sc8;
  const uint soff = (uint)(srow*128 + ((sc8*2) ^ ((srow&7)<<4)));

  auto stage = [&](int s){
    const float4 v0 = *(const float4*)(xbase + (size_t)s*64);
    const float4 v1 = *(const float4*)(xbase + (size_t)s*64 + 4);
    const float vv[8] = {v0.x,v0.y,v0.z,v0.w,v1.x,v1.y,v1.z,v1.w};
    f16x8 hv, lv;
#pragma unroll
    for (int i=0;i<8;i++){
      const _Float16 h = (_Float16)vv[i];
      hv[i] = h;
      lv[i] = (_Float16)((vv[i] - (float)h) * 256.f);
    }
    const uint base = (uint)((s & 1) * 16384);
    *(f16x8*)(smem + base + soff)        = hv;   // A_hi
    *(f16x8*)(smem + base + 8192 + soff) = lv;   // A_lo*256
  };

  auto compute = [&](int s){
    const uint abase = (uint)((s & 1) * 16384);
#pragma unroll
    for (int kk=0; kk<2; kk++){
      f16x8 ah[2], al[2];
#pragma unroll
      for (int mf=0; mf<2; mf++){
        const int mrow = wm*32 + mf*16 + (lane & 15);
        const uint kb = (uint)(kk*64 + ((lane >> 4) * 16));
        const uint ad = abase + (uint)(mrow*128) + (kb ^ (uint)((mrow & 7) << 4));
        ah[mf] = *(const f16x8*)(smem + ad);
        al[mf] = *(const f16x8*)(smem + ad + 8192);
      }
#pragma unroll
      for (int nf=0; nf<8; nf++){
        const int ncol = wn*128 + nf*16 + (lane & 15);
        const size_t bo = (size_t)ncol*DIM + (size_t)s*64 + kk*32 + ((lane >> 4) * 8);
        const f16x8 bh = *(const f16x8*)(Chi + bo);
        const f16x8 bl = *(const f16x8*)(Clo + bo);
        accA[0][nf] = __builtin_amdgcn_mfma_f32_16x16x32_f16(ah[0], bh, accA[0][nf], 0,0,0);
        accA[1][nf] = __builtin_amdgcn_mfma_f32_16x16x32_f16(ah[1], bh, accA[1][nf], 0,0,0);
        accB[0][nf] = __builtin_amdgcn_mfma_f32_16x16x32_f16(ah[0], bl, accB[0][nf], 0,0,0);
        accB[1][nf] = __builtin_amdgcn_mfma_f32_16x16x32_f16(ah[1], bl, accB[1][nf], 0,0,0);
        accB[0][nf] = __builtin_amdgcn_mfma_f32_16x16x32_f16(al[0], bh, accB[0][nf], 0,0,0);
        accB[1][nf] = __builtin_amdgcn_mfma_f32_16x16x32_f16(al[1], bh, accB[1][nf], 0,0,0);
      }
    }
  };

  stage(0);
  __syncthreads();
  for (int s=0; s<12; s++){
    if (s+1 < 12) stage(s+1);
    compute(s);
    __syncthreads();
  }

  // epilogue: S = accA + accB/256; write S[c][tok] swizzled:
  // byte = c*256 + ((tok*4) ^ ((c&7)<<4))
#pragma unroll
  for (int mf=0; mf<2; mf++)
#pragma unroll
    for (int nf=0; nf<8; nf++){
      const f32x4 a = accA[mf][nf] + 0.00390625f * accB[mf][nf];
      const int n = wn*128 + nf*16 + (lane & 15);
      const int m = wm*32 + mf*16 + ((lane >> 4) * 4);
      const uint sb = (uint)(n*256) + (uint)((m*4) ^ ((n & 7) << 4));
      *(f32x4*)(smem + sb) = a;
    }
  __syncthreads();

  // argmin chain. Wave w owns candidate rows c with c%8==w (scan + update),
  // so no barrier is needed between update(l) and scan(l+1) on S.
  double* part_val = (double*)(smem + 131072);
  unsigned short* part_idx = (unsigned short*)(smem + 135168);
  const float* __restrict__ cn = (const float*)(ws + WS_CNORM);
  const float* __restrict__ G  = (const float*)(ws + WS_G);
  const int off[8] = {0,2,6,14,30,62,126,254};
  const int KK[8]  = {2,4,8,16,32,64,128,256};
  int gsel[8];
#pragma unroll
  for (int l=0; l<8; l++){
    const int cs = off[l], ce = off[l] + KK[l];
    const int c0 = cs + (((w - cs) % 8 + 8) % 8);
    double bv = 1e30; int bc = 0x7fff;
    for (int c = c0; c < ce; c += 8){
      const float sv = *(const float*)(smem + (uint)(c*256) + (uint)((lane*4) ^ ((c & 7) << 4)));
      const double sc = (double)cn[c] - 2.0*(double)sv;
      if (sc < bv){ bv = sc; bc = c; }
    }
    part_val[w*64 + lane] = bv;
    part_idx[w*64 + lane] = (unsigned short)bc;
    __syncthreads();
    double mv = part_val[lane]; int mc = part_idx[lane];
#pragma unroll
    for (int j=1;j<8;j++){
      const double v = part_val[j*64 + lane];
      const int c2 = part_idx[j*64 + lane];
      if (v < mv || (v == mv && c2 < mc)){ mv = v; mc = c2; }
    }
    gsel[l] = mc;
    __syncthreads();   // part[] reads done before next layer rewrites
    if (l < 7){
      const int ns = off[l+1];
      const int c0u = ns + (((w - ns) % 8 + 8) % 8);
      const int gme = gsel[l];
      for (int c = c0u; c < NC; c += 8){
        const float corr = G[(size_t)c*NCB + gme];   // G symmetric: G[c][g]
        float* sp = (float*)(smem + (uint)(c*256) + (uint)((lane*4) ^ ((c & 7) << 4)));
        *sp -= corr;
      }
    }
  }
  if (w == 0){
    int* idxw = (int*)(ws + WS_IDX);
    const size_t tokg = (size_t)blk*64 + lane;
#pragma unroll
    for (int l=0;l<8;l++) idxw[tokg*8 + l] = gsel[l] - off[l];
  }
}

// Finalize: quantized = sum of chosen codewords, commit-loss partials, idx floats.
__global__ __launch_bounds__(512) void k_fin(const float* __restrict__ x,
                                             char* __restrict__ ws,
                                             float* __restrict__ out){
  const int t = threadIdx.x, lane = t & 63, w = t >> 6;
  const size_t tok = (size_t)blockIdx.x * 8 + w;
  const int off[8] = {0,2,6,14,30,62,126,254};
  const int* __restrict__ idxw = (const int*)(ws + WS_IDX);
  const float* __restrict__ C32 = (const float*)(ws + WS_C32);
  int loc[8];
#pragma unroll
  for (int l=0;l<8;l++) loc[l] = idxw[tok*8 + l];
  if (lane < 8) out[(size_t)NTOK*DIM + tok*8 + lane] = (float)idxw[tok*8 + lane];

  const float4* __restrict__ xr = (const float4*)(x + tok*DIM);
  float4* __restrict__ qr = (float4*)(out + tok*DIM);
  const float4* crow[8];
#pragma unroll
  for (int l=0;l<8;l++) crow[l] = (const float4*)(C32 + (size_t)(loc[l] + off[l])*DIM);
  float ssq = 0.f;
#pragma unroll
  for (int i=0;i<3;i++){
    const int e4 = i*64 + lane;
    const float4 xv = xr[e4];
    float rx = xv.x, ry = xv.y, rz = xv.z, rw = xv.w;
    float qx = 0.f, qy = 0.f, qz = 0.f, qw = 0.f;
#pragma unroll
    for (int l=0;l<8;l++){
      const float4 cv = crow[l][e4];
      rx -= cv.x; ry -= cv.y; rz -= cv.z; rw -= cv.w;
      qx += cv.x; qy += cv.y; qz += cv.z; qw += cv.w;
      ssq += rx*rx + ry*ry + rz*rz + rw*rw;
    }
    float4 q; q.x = qx; q.y = qy; q.z = qz; q.w = qw;
    qr[e4] = q;
  }
#pragma unroll
  for (int d=32; d>0; d>>=1) ssq += __shfl_down(ssq, d);
  __shared__ float bsum[8];
  if (lane == 0) bsum[w] = ssq;
  __syncthreads();
  if (t == 0){
    float s2 = 0.f;
#pragma unroll
    for (int j=0;j<8;j++) s2 += bsum[j];
    atomicAdd((float*)(ws + WS_ACC), s2);
  }
}

__global__ void k_loss(const char* __restrict__ ws, float* __restrict__ out){
  if (threadIdx.x == 0)
    out[(size_t)NTOK*DIM + (size_t)NTOK*8] =
      0.25f * (*(const float*)(ws + WS_ACC)) / (float)((size_t)NTOK * DIM);
}

extern "C" void kernel_launch(void* const* d_in, const int* in_sizes, int n_in,
                              void* d_out, int out_size, void* d_ws, size_t ws_size,
                              hipStream_t stream){
  const float* x = (const float*)d_in[0];
  char* ws = (char*)d_ws;
  float* out = (float*)d_out;
  k_prep<<<512, 256, 0, stream>>>((const float*)d_in[1], (const float*)d_in[2],
                                  (const float*)d_in[3], (const float*)d_in[4],
                                  (const float*)d_in[5], (const float*)d_in[6],
                                  (const float*)d_in[7], (const float*)d_in[8], ws);
  k_gram<<<512, 256, 0, stream>>>(ws);
  k_main<<<1024, 512, 0, stream>>>(x, ws);
  k_fin<<<8192, 512, 0, stream>>>(x, ws, out);
  k_loss<<<1, 64, 0, stream>>>(ws, out);
}

// Round 3
// 543.329 us; speedup vs baseline: 1.7823x; 1.7823x over previous
//
#include <hip/hip_runtime.h>
#include <stdint.h>

#define NTOK 65536
#define DIM  768
#define NCB  512
#define NC   510

typedef _Float16 f16x8 __attribute__((ext_vector_type(8)));
typedef float f32x4 __attribute__((ext_vector_type(4)));

// ws byte offsets
#define WS_C32   0u          // 512*768*4
#define WS_CHI   1572864u    // 512*768*2   (f16 hi)
#define WS_CLO   2359296u    // 512*768*2   (f16 (x-hi)*256)
#define WS_CNORM 3145728u    // 512*4
#define WS_G     3147776u    // 512*512*4
#define WS_IDX   4196352u    // 65536*8*4
#define WS_ACC   6293504u    // 4
#define WS_S     8388608u    // 65536*512*4 = 134217728 (if ws_size permits)

__device__ __forceinline__ void gl_lds16(const void* g, void* l){
  __builtin_amdgcn_global_load_lds(
      (const __attribute__((address_space(1))) unsigned int*)g,
      (__attribute__((address_space(3))) unsigned int*)l,
      16, 0, 0);
}

__global__ void k_prep(const float* __restrict__ cb0, const float* __restrict__ cb1,
                       const float* __restrict__ cb2, const float* __restrict__ cb3,
                       const float* __restrict__ cb4, const float* __restrict__ cb5,
                       const float* __restrict__ cb6, const float* __restrict__ cb7,
                       char* __restrict__ ws){
  const int r = blockIdx.x, t = threadIdx.x;
  const float* srcs[8] = {cb0,cb1,cb2,cb3,cb4,cb5,cb6,cb7};
  const int off[8] = {0,2,6,14,30,62,126,254};
  const int KK[8]  = {2,4,8,16,32,64,128,256};
  const float* src = nullptr;
#pragma unroll
  for (int l=0;l<8;l++)
    if (r >= off[l] && r < off[l]+KK[l]) src = srcs[l] + (size_t)(r - off[l]) * DIM;
  float* C32 = (float*)(ws + WS_C32);
  _Float16* Chi = (_Float16*)(ws + WS_CHI);
  _Float16* Clo = (_Float16*)(ws + WS_CLO);
  double ss = 0.0;
#pragma unroll
  for (int i=0;i<3;i++){
    const int e = t + i*256;
    const float v = src ? src[e] : 0.f;
    C32[(size_t)r*DIM + e] = v;
    const _Float16 h = (_Float16)v;
    Chi[(size_t)r*DIM + e] = h;
    Clo[(size_t)r*DIM + e] = (_Float16)((v - (float)h) * 256.f);
    ss += (double)v * (double)v;
  }
  __shared__ double red[256];
  red[t] = ss; __syncthreads();
  for (int sdown=128; sdown>0; sdown>>=1){
    if (t < sdown) red[t] += red[t+sdown];
    __syncthreads();
  }
  if (t == 0){
    float* cnp = (float*)(ws + WS_CNORM);
    cnp[r] = (r < NC) ? (float)red[0] : 1e30f;
    if (r == 0) *(float*)(ws + WS_ACC) = 0.f;
  }
}

__global__ void k_gram(char* __restrict__ ws){
  const int i = blockIdx.x, t = threadIdx.x;
  const float* __restrict__ C32 = (const float*)(ws + WS_C32);
  __shared__ float row[DIM];
  for (int e=t; e<DIM; e+=256) row[e] = C32[(size_t)i*DIM + e];
  __syncthreads();
  float* __restrict__ G = (float*)(ws + WS_G);
  for (int j=t; j<NCB; j+=256){
    const float4* cj = (const float4*)(C32 + (size_t)j*DIM);
    double d = 0.0;
    for (int k=0; k<DIM/4; k++){
      const float4 b = cj[k];
      d += (double)row[4*k]*(double)b.x + (double)row[4*k+1]*(double)b.y
         + (double)row[4*k+2]*(double)b.z + (double)row[4*k+3]*(double)b.w;
    }
    G[(size_t)i*NCB + j] = (float)d;
  }
}

// S = x @ C_all^T  (f16 hi/lo dual-accumulator, 3 MFMA/term-set)
// 128x128 tile, BK=64, 4 waves (2Mx2N), single 64KB LDS buffer -> 2 blocks/CU.
// A: reg-staged f32->f16 with XOR-swizzled ds_write; B: global_load_lds w/
// pre-swizzled source (linear dest + inverse-swz source + swz read).
__global__ __launch_bounds__(256, 2) void k_gemm(const float* __restrict__ x,
                                                 const char* __restrict__ ws,
                                                 float* __restrict__ S){
  __shared__ __align__(16) char smem[65536];
  const int t = threadIdx.x, lane = t & 63, w = t >> 6;
  const int wm = w >> 1, wn = w & 1;
  const int bid = blockIdx.x;
  const int nt = bid >> 9, mt = bid & 511;
  const _Float16* __restrict__ Chi = (const _Float16*)(ws + WS_CHI);
  const _Float16* __restrict__ Clo = (const _Float16*)(ws + WS_CLO);

  f32x4 accA[4][4], accB[4][4];
#pragma unroll
  for (int i=0;i<4;i++)
#pragma unroll
    for (int j=0;j<4;j++){ accA[i][j] = {0.f,0.f,0.f,0.f}; accB[i][j] = {0.f,0.f,0.f,0.f}; }

  // A staging: thread t covers row ar = t&127, k-half h = t>>7 (32 f32)
  const int ar = t & 127, hh = t >> 7;
  const float* __restrict__ xrow = x + (size_t)(mt*128 + ar)*DIM + hh*32;

  float vv[32];
  auto loadA = [&](int kt){
    const float4* p = (const float4*)(xrow + kt*64);
#pragma unroll
    for (int q=0;q<8;q++){
      const float4 v = p[q];
      vv[q*4] = v.x; vv[q*4+1] = v.y; vv[q*4+2] = v.z; vv[q*4+3] = v.w;
    }
  };
  auto writeA = [&](){
#pragma unroll
    for (int q=0;q<4;q++){
      f16x8 hv, lv;
#pragma unroll
      for (int e=0;e<8;e++){
        const float f = vv[q*8+e];
        const _Float16 hf = (_Float16)f;
        hv[e] = hf;
        lv[e] = (_Float16)((f - (float)hf) * 256.f);
      }
      const uint wb = (uint)(ar*128 + (((hh*4+q) ^ (ar&7))*16));
      *(f16x8*)(smem + wb) = hv;
      *(f16x8*)(smem + 16384 + wb) = lv;
    }
  };
  auto stageB = [&](int kt){
#pragma unroll
    for (int c4=0;c4<4;c4++){
      const int r0 = w*32 + c4*8;
      const int rloc = r0 + (lane>>3);
      const int jsrc = (lane&7) ^ (rloc&7);
      const size_t go = (size_t)(nt*128 + rloc)*DIM + (size_t)kt*64 + jsrc*8;
      gl_lds16(Chi + go, smem + 32768 + r0*128);
      gl_lds16(Clo + go, smem + 49152 + r0*128);
    }
  };
  auto compute = [&](int kk){
    f16x8 fa[4], fal[4], fb[4], fbl[4];
#pragma unroll
    for (int mf=0;mf<4;mf++){
      const int m = wm*64 + mf*16 + (lane&15);
      const uint ab = (uint)(m*128 + ((((kk<<2)+(lane>>4)) ^ (m&7))*16));
      fa[mf]  = *(const f16x8*)(smem + ab);
      fal[mf] = *(const f16x8*)(smem + 16384 + ab);
    }
#pragma unroll
    for (int nf=0;nf<4;nf++){
      const int c = wn*64 + nf*16 + (lane&15);
      const uint bb = (uint)(c*128 + ((((kk<<2)+(lane>>4)) ^ (c&7))*16));
      fb[nf]  = *(const f16x8*)(smem + 32768 + bb);
      fbl[nf] = *(const f16x8*)(smem + 49152 + bb);
    }
#pragma unroll
    for (int mf=0;mf<4;mf++)
#pragma unroll
      for (int nf=0;nf<4;nf++){
        accA[mf][nf] = __builtin_amdgcn_mfma_f32_16x16x32_f16(fa[mf],  fb[nf],  accA[mf][nf], 0,0,0);
        accB[mf][nf] = __builtin_amdgcn_mfma_f32_16x16x32_f16(fa[mf],  fbl[nf], accB[mf][nf], 0,0,0);
        accB[mf][nf] = __builtin_amdgcn_mfma_f32_16x16x32_f16(fal[mf], fb[nf],  accB[mf][nf], 0,0,0);
      }
  };

  loadA(0);
  for (int kt=0; kt<12; kt++){
    writeA();
    stageB(kt);
    __syncthreads();
    if (kt < 11) loadA(kt+1);   // prefetch next A into regs under compute
    compute(0);
    compute(1);
    __syncthreads();
  }

#pragma unroll
  for (int mf=0;mf<4;mf++)
#pragma unroll
    for (int nf=0;nf<4;nf++){
      const f32x4 v = accA[mf][nf] + 0.00390625f * accB[mf][nf];
      const int col  = nt*128 + wn*64 + nf*16 + (lane&15);
      const int row0 = mt*128 + wm*64 + mf*16 + ((lane>>4)<<2);
#pragma unroll
      for (int e=0;e<4;e++)
        S[(size_t)(row0+e)*NCB + col] = v[e];
    }
}

// Per-token argmin chain: 1 wave/token, Gram row-gathers, f64 compare.
__global__ __launch_bounds__(256) void k_chain(const float* __restrict__ S,
                                               char* __restrict__ ws){
  const int lane = threadIdx.x & 63, w = threadIdx.x >> 6;
  const size_t tok = (size_t)blockIdx.x*4 + w;
  const float* __restrict__ cn = (const float*)(ws + WS_CNORM);
  const float* __restrict__ G  = (const float*)(ws + WS_G);
  float sv[8], cnv[8];
#pragma unroll
  for (int k=0;k<8;k++){
    sv[k]  = S[tok*NCB + k*64 + lane];
    cnv[k] = cn[k*64 + lane];
  }
  const int off[8] = {0,2,6,14,30,62,126,254};
  const int KK[8]  = {2,4,8,16,32,64,128,256};
  int gsel[8];
#pragma unroll
  for (int l=0;l<8;l++){
    const int cs = off[l], ce = off[l] + KK[l];
    double bv = 1e300; int bc = 0x7fffffff;
#pragma unroll
    for (int k=0;k<8;k++){
      const int c = k*64 + lane;
      if (c >= cs && c < ce){
        const double s = (double)cnv[k] - 2.0*(double)sv[k];
        if (s < bv){ bv = s; bc = c; }
      }
    }
#pragma unroll
    for (int d=1; d<64; d<<=1){
      const double ov = __shfl_xor(bv, d);
      const int    oc = __shfl_xor(bc, d);
      if (ov < bv || (ov == bv && oc < bc)){ bv = ov; bc = oc; }
    }
    gsel[l] = bc;
    if (l < 7){
      const float* __restrict__ gr = G + (size_t)bc*NCB;
#pragma unroll
      for (int k=0;k<8;k++) sv[k] -= gr[k*64 + lane];
    }
  }
  if (lane == 0){
    int* idxw = (int*)(ws + WS_IDX);
#pragma unroll
    for (int l=0;l<8;l++) idxw[tok*8 + l] = gsel[l] - off[l];
  }
}

// Finalize: quantized = sum of chosen codewords, commit-loss partials, idx floats.
__global__ __launch_bounds__(512) void k_fin(const float* __restrict__ x,
                                             char* __restrict__ ws,
                                             float* __restrict__ out){
  const int t = threadIdx.x, lane = t & 63, w = t >> 6;
  const size_t tok = (size_t)blockIdx.x * 8 + w;
  const int off[8] = {0,2,6,14,30,62,126,254};
  const int* __restrict__ idxw = (const int*)(ws + WS_IDX);
  const float* __restrict__ C32 = (const float*)(ws + WS_C32);
  int loc[8];
#pragma unroll
  for (int l=0;l<8;l++) loc[l] = idxw[tok*8 + l];
  if (lane < 8) out[(size_t)NTOK*DIM + tok*8 + lane] = (float)idxw[tok*8 + lane];

  const float4* __restrict__ xr = (const float4*)(x + tok*DIM);
  float4* __restrict__ qr = (float4*)(out + tok*DIM);
  const float4* crow[8];
#pragma unroll
  for (int l=0;l<8;l++) crow[l] = (const float4*)(C32 + (size_t)(loc[l] + off[l])*DIM);
  float ssq = 0.f;
#pragma unroll
  for (int i=0;i<3;i++){
    const int e4 = i*64 + lane;
    const float4 xv = xr[e4];
    float rx = xv.x, ry = xv.y, rz = xv.z, rw = xv.w;
    float qx = 0.f, qy = 0.f, qz = 0.f, qw = 0.f;
#pragma unroll
    for (int l=0;l<8;l++){
      const float4 cv = crow[l][e4];
      rx -= cv.x; ry -= cv.y; rz -= cv.z; rw -= cv.w;
      qx += cv.x; qy += cv.y; qz += cv.z; qw += cv.w;
      ssq += rx*rx + ry*ry + rz*rz + rw*rw;
    }
    float4 q; q.x = qx; q.y = qy; q.z = qz; q.w = qw;
    qr[e4] = q;
  }
#pragma unroll
  for (int d=32; d>0; d>>=1) ssq += __shfl_down(ssq, d);
  __shared__ float bsum[8];
  if (lane == 0) bsum[w] = ssq;
  __syncthreads();
  if (t == 0){
    float s2 = 0.f;
#pragma unroll
    for (int j=0;j<8;j++) s2 += bsum[j];
    atomicAdd((float*)(ws + WS_ACC), s2);
  }
}

__global__ void k_loss(const char* __restrict__ ws, float* __restrict__ out){
  if (threadIdx.x == 0)
    out[(size_t)NTOK*DIM + (size_t)NTOK*8] =
      0.25f * (*(const float*)(ws + WS_ACC)) / (float)((size_t)NTOK * DIM);
}

extern "C" void kernel_launch(void* const* d_in, const int* in_sizes, int n_in,
                              void* d_out, int out_size, void* d_ws, size_t ws_size,
                              hipStream_t stream){
  const float* x = (const float*)d_in[0];
  char* ws = (char*)d_ws;
  float* out = (float*)d_out;
  // S scratch: prefer ws; else use d_out as scratch (fully consumed by k_chain
  // before k_fin rewrites every element of d_out).
  float* Sp = (ws_size >= (size_t)(WS_S + 134217728u)) ? (float*)(ws + WS_S) : out;
  k_prep<<<512, 256, 0, stream>>>((const float*)d_in[1], (const float*)d_in[2],
                                  (const float*)d_in[3], (const float*)d_in[4],
                                  (const float*)d_in[5], (const float*)d_in[6],
                                  (const float*)d_in[7], (const float*)d_in[8], ws);
  k_gram<<<512, 256, 0, stream>>>(ws);
  k_gemm<<<2048, 256, 0, stream>>>(x, ws, Sp);
  k_chain<<<16384, 256, 0, stream>>>(Sp, ws);
  k_fin<<<8192, 512, 0, stream>>>(x, ws, out);
  k_loss<<<1, 64, 0, stream>>>(ws, out);
}